// Round 1
// baseline (559.366 us; speedup 1.0000x reference)
//
#include <hip/hip_runtime.h>

typedef unsigned short u16;
typedef __bf16 bfx8 __attribute__((ext_vector_type(8)));
typedef float f32x4 __attribute__((ext_vector_type(4)));

#define MFMA16(a,b,c) __builtin_amdgcn_mfma_f32_16x16x32_bf16(a,b,c,0,0,0)

// ---------- helpers ----------
__device__ __forceinline__ u16 f2bf(float f) {
  union { float f; unsigned u; } v; v.f = f;
  unsigned r = v.u + 0x7fffu + ((v.u >> 16) & 1u);   // RNE
  return (u16)(r >> 16);
}

__device__ __forceinline__ void gld16(const void* g, void* l) {
  __builtin_amdgcn_global_load_lds(
      (const __attribute__((address_space(1))) unsigned int*)g,
      (__attribute__((address_space(3))) unsigned int*)l, 16, 0, 0);
}

// ---------- f32 -> bf16 elementwise (x) ----------
__global__ void convert_bf16_k(const float* __restrict__ in, u16* __restrict__ outp, int nvec) {
  int i = blockIdx.x * 256 + threadIdx.x;
  if (i >= nvec) return;
  float4 v = ((const float4*)in)[i];
  unsigned lo = (unsigned)f2bf(v.x) | ((unsigned)f2bf(v.y) << 16);
  unsigned hi = (unsigned)f2bf(v.z) | ((unsigned)f2bf(v.w) << 16);
  ((uint2*)outp)[i] = make_uint2(lo, hi);
}

// ---------- W [K,N] f32 -> Wt [N,K] bf16 (LDS tile transpose) ----------
__global__ void transpose_k(const float* __restrict__ W, u16* __restrict__ Wt, int K, int N) {
  __shared__ float tile[32][33];
  int n0 = blockIdx.x * 32, k0 = blockIdx.y * 32;
  int tx = threadIdx.x, ty = threadIdx.y;  // (32, 8)
  #pragma unroll
  for (int i = 0; i < 4; i++)
    tile[ty * 4 + i][tx] = W[(size_t)(k0 + ty * 4 + i) * N + n0 + tx];
  __syncthreads();
  #pragma unroll
  for (int i = 0; i < 4; i++)
    Wt[(size_t)(n0 + ty * 4 + i) * K + k0 + tx] = f2bf(tile[tx][ty * 4 + i]);
}

// ---------- bf16 GEMM: C[M,N] f32 = A[M,K] @ Bt[N,K]^T  (m97 structure) ----------
__global__ __launch_bounds__(256) void gemm_bf16(
    const u16* __restrict__ A, const u16* __restrict__ Bt,
    float* __restrict__ C, int M, int N, int K)
{
  __shared__ u16 As[128 * 32];
  __shared__ u16 Bs[128 * 32];
  const int tid = threadIdx.x;
  const int lane = tid & 63, w = tid >> 6;
  const int wm = w >> 1, wn = w & 1;
  const int lrow = lane & 15, lg = lane >> 4, lk = lg * 8;
  const int m0 = blockIdx.y * 128, n0 = blockIdx.x * 128;
  f32x4 acc[4][4] = {};

  const int r0 = tid >> 2, kc = (tid & 3) * 8;
  const u16* Ag = A + (size_t)(m0 + r0) * K + kc;
  const u16* Bg = Bt + (size_t)(n0 + r0) * K + kc;
  u16* Al0 = As + w * 512;
  u16* Al1 = As + 2048 + w * 512;
  u16* Bl0 = Bs + w * 512;
  u16* Bl1 = Bs + 2048 + w * 512;

  for (int k0 = 0; k0 < K; k0 += 32) {
    gld16(Ag + k0, Al0);
    gld16(Ag + (size_t)64 * K + k0, Al1);
    gld16(Bg + k0, Bl0);
    gld16(Bg + (size_t)64 * K + k0, Bl1);
    __syncthreads();
    bfx8 af[4], bff[4];
    #pragma unroll
    for (int i = 0; i < 4; i++) {
      af[i]  = *(const bfx8*)(As + (wm * 64 + i * 16 + lrow) * 32 + lk);
      bff[i] = *(const bfx8*)(Bs + (wn * 64 + i * 16 + lrow) * 32 + lk);
    }
    #pragma unroll
    for (int i = 0; i < 4; i++)
      #pragma unroll
      for (int j = 0; j < 4; j++)
        acc[i][j] = MFMA16(af[i], bff[j], acc[i][j]);
    __syncthreads();
  }
  #pragma unroll
  for (int i = 0; i < 4; i++) {
    int row = m0 + wm * 64 + i * 16 + lg * 4;
    #pragma unroll
    for (int j = 0; j < 4; j++) {
      int col = n0 + wn * 64 + j * 16 + lrow;
      float* cp = C + (size_t)row * N + col;
      #pragma unroll
      for (int r = 0; r < 4; r++) cp[(size_t)r * N] = acc[i][j][r];
    }
  }
}

// ---------- RoPE: Cqkv [4096,3072] f32 -> dst [B,nh,S,64] bf16 ----------
__global__ void rope_k(const float* __restrict__ Cq, const float* __restrict__ cosT,
                       const float* __restrict__ sinT, u16* __restrict__ dst,
                       int nheads, int col_off)
{
  int idx = blockIdx.x * 256 + threadIdx.x;
  int total = 2 * 2048 * nheads * 32;
  if (idx >= total) return;
  int d = idx & 31;
  int h = (idx >> 5) % nheads;
  int sm = idx / (32 * nheads);          // b*2048 + s
  int s = sm & 2047, b = sm >> 11;
  const float* row = Cq + (size_t)sm * 3072 + col_off + h * 64;
  float q1 = row[d], q2 = row[d + 32];
  float c1 = cosT[s * 64 + d], c2 = cosT[s * 64 + d + 32];
  float s1 = sinT[s * 64 + d], s2 = sinT[s * 64 + d + 32];
  float o1 = q1 * c1 - q2 * s1;
  float o2 = q2 * c2 + q1 * s2;
  u16* drow = dst + ((size_t)(b * nheads + h) * 2048 + s) * 64;
  drow[d] = f2bf(o1);
  drow[d + 32] = f2bf(o2);
}

// ---------- V slice convert: Cqkv -> Vb [B,KV,S,64] bf16 ----------
__global__ void vconv_k(const float* __restrict__ Cq, u16* __restrict__ Vb) {
  int idx = blockIdx.x * 256 + threadIdx.x;  // B*S*KV*64
  if (idx >= 2 * 2048 * 8 * 64) return;
  int d = idx & 63;
  int g = (idx >> 6) & 7;
  int sm = idx >> 9;                        // b*2048 + s
  int s = sm & 2047, b = sm >> 11;
  float v = Cq[(size_t)sm * 3072 + 2560 + g * 64 + d];
  Vb[((size_t)(b * 8 + g) * 2048 + s) * 64 + d] = f2bf(v);
}

// ---------- causal flash attention, GQA ----------
// grid (S/64, H, B), 256 thr. Wave w owns q rows qt*64 + w*16 .. +15.
__global__ __launch_bounds__(256) void attn_k(
    const u16* __restrict__ Qb, const u16* __restrict__ Kb,
    const u16* __restrict__ Vb, u16* __restrict__ Aout)
{
  __shared__ u16 Vt[64 * 32];      // [d][key]
  __shared__ u16 Ps[4 * 16 * 32];  // per-wave [q][key]
  const int qt = blockIdx.x, h = blockIdx.y, b = blockIdx.z;
  const int kvh = h >> 2;
  const int tid = threadIdx.x, lane = tid & 63, w = tid >> 6;
  const int lrow = lane & 15, lg = lane >> 4, lk = lg * 8;
  const int qrow_w = qt * 64 + w * 16;

  const u16* Qp = Qb + ((size_t)(b * 32 + h) * 2048 + qrow_w + lrow) * 64;
  bfx8 qf0 = *(const bfx8*)(Qp + lk);
  bfx8 qf1 = *(const bfx8*)(Qp + 32 + lk);
  const u16* Kp = Kb + (size_t)(b * 8 + kvh) * 2048 * 64;
  const u16* Vp = Vb + (size_t)(b * 8 + kvh) * 2048 * 64;

  f32x4 oacc[4] = {};
  float mrow[4] = {-1e30f, -1e30f, -1e30f, -1e30f};
  float lsum[4] = {0.f, 0.f, 0.f, 0.f};

  const int vkey = tid >> 3, vd0 = (tid & 7) * 8;
  const int nkt = qt * 2 + 2;
  for (int kt = 0; kt < nkt; kt++) {
    const int kb = kt * 32;
    {  // stage V transposed
      uint4 vv = *(const uint4*)(Vp + (size_t)(kb + vkey) * 64 + vd0);
      const u16* pv = (const u16*)&vv;
      #pragma unroll
      for (int j = 0; j < 8; j++) Vt[(vd0 + j) * 32 + vkey] = pv[j];
    }
    // S = Q K^T (16q x 32k per wave)
    f32x4 sf[2];
    #pragma unroll
    for (int nf = 0; nf < 2; nf++) {
      const u16* Kr = Kp + (size_t)(kb + nf * 16 + lrow) * 64 + lk;
      bfx8 k0 = *(const bfx8*)(Kr);
      bfx8 k1 = *(const bfx8*)(Kr + 32);
      f32x4 z = {};
      z = MFMA16(qf0, k0, z);
      z = MFMA16(qf1, k1, z);
      sf[nf] = z;
    }
    // mask + scale + online softmax
    float p0[4], p1[4], tm[4];
    #pragma unroll
    for (int r = 0; r < 4; r++) {
      int row = qrow_w + lg * 4 + r;
      float s0 = sf[0][r] * 0.125f, s1 = sf[1][r] * 0.125f;
      if (kb + lrow > row) s0 = -1e30f;
      if (kb + 16 + lrow > row) s1 = -1e30f;
      p0[r] = s0; p1[r] = s1;
      tm[r] = fmaxf(s0, s1);
    }
    #pragma unroll
    for (int off = 1; off < 16; off <<= 1)
      #pragma unroll
      for (int r = 0; r < 4; r++) tm[r] = fmaxf(tm[r], __shfl_xor(tm[r], off, 64));
    float rs[4];
    #pragma unroll
    for (int r = 0; r < 4; r++) {
      float mnew = fmaxf(mrow[r], tm[r]);
      float corr = __expf(mrow[r] - mnew);
      mrow[r] = mnew;
      float e0 = __expf(p0[r] - mnew);
      float e1 = __expf(p1[r] - mnew);
      p0[r] = e0; p1[r] = e1;
      rs[r] = e0 + e1;
      lsum[r] *= corr;
      #pragma unroll
      for (int f = 0; f < 4; f++) oacc[f][r] *= corr;
    }
    #pragma unroll
    for (int off = 1; off < 16; off <<= 1)
      #pragma unroll
      for (int r = 0; r < 4; r++) rs[r] += __shfl_xor(rs[r], off, 64);
    #pragma unroll
    for (int r = 0; r < 4; r++) {
      lsum[r] += rs[r];
      Ps[(w * 16 + lg * 4 + r) * 32 + lrow] = f2bf(p0[r]);
      Ps[(w * 16 + lg * 4 + r) * 32 + 16 + lrow] = f2bf(p1[r]);
    }
    __syncthreads();  // Vt + Ps visible
    bfx8 pf = *(const bfx8*)(Ps + (w * 16 + lrow) * 32 + lk);
    #pragma unroll
    for (int f = 0; f < 4; f++) {
      bfx8 vf = *(const bfx8*)(Vt + (f * 16 + lrow) * 32 + lk);
      oacc[f] = MFMA16(pf, vf, oacc[f]);
    }
    __syncthreads();  // done with Vt/Ps before next overwrite
  }
  #pragma unroll
  for (int r = 0; r < 4; r++) {
    float inv = 1.f / lsum[r];
    int row = qrow_w + lg * 4 + r;
    u16* op = Aout + ((size_t)b * 2048 + row) * 2048 + h * 64;
    #pragma unroll
    for (int f = 0; f < 4; f++) op[f * 16 + lrow] = f2bf(oacc[f][r] * inv);
  }
}

// ---------- launch ----------
extern "C" void kernel_launch(void* const* d_in, const int* in_sizes, int n_in,
                              void* d_out, int out_size, void* d_ws, size_t ws_size,
                              hipStream_t stream) {
  const float* x    = (const float*)d_in[0];
  const float* cosT = (const float*)d_in[1];
  const float* sinT = (const float*)d_in[2];
  const float* Wq   = (const float*)d_in[3];
  const float* Wk   = (const float*)d_in[4];
  const float* Wv   = (const float*)d_in[5];
  const float* Wo   = (const float*)d_in[6];
  float* out = (float*)d_out;
  char* ws = (char*)d_ws;

  // workspace layout (aliased; total 88,080,384 B)
  u16* xb    = (u16*)(ws);                          // 16,777,216
  u16* WqkvT = (u16*)(ws + 16777216);               // 12,582,912
  u16* Qb    = (u16*)(ws);                          // alias over xb
  u16* Kb    = (u16*)(ws + 16777216);               // alias over WqkvT
  u16* Vb    = (u16*)(ws + 16777216 + 4194304);
  u16* WoT   = (u16*)(ws + 29360128);               // 8,388,608
  float* Cqkv = (float*)(ws + 37748736);            // 50,331,648
  u16* Aout  = (u16*)(ws + 37748736);               // alias over dead Cqkv

  dim3 tb(32, 8);
  convert_bf16_k<<<8192, 256, 0, stream>>>(x, xb, 2097152);
  transpose_k<<<dim3(64, 64), tb, 0, stream>>>(Wq, WqkvT, 2048, 2048);
  transpose_k<<<dim3(16, 64), tb, 0, stream>>>(Wk, WqkvT + (size_t)2048 * 2048, 2048, 512);
  transpose_k<<<dim3(16, 64), tb, 0, stream>>>(Wv, WqkvT + (size_t)2560 * 2048, 2048, 512);
  transpose_k<<<dim3(64, 64), tb, 0, stream>>>(Wo, WoT, 2048, 2048);

  gemm_bf16<<<dim3(24, 32), 256, 0, stream>>>(xb, WqkvT, Cqkv, 4096, 3072, 2048);

  rope_k<<<16384, 256, 0, stream>>>(Cqkv, cosT, sinT, Qb, 32, 0);
  rope_k<<<4096, 256, 0, stream>>>(Cqkv, cosT, sinT, Kb, 8, 2048);
  vconv_k<<<8192, 256, 0, stream>>>(Cqkv, Vb);

  attn_k<<<dim3(32, 32, 2), 256, 0, stream>>>(Qb, Kb, Vb, Aout);

  gemm_bf16<<<dim3(16, 32), 256, 0, stream>>>(Aout, WoT, out, 4096, 2048, 2048);
}

// Round 2
// 409.094 us; speedup vs baseline: 1.3673x; 1.3673x over previous
//
#include <hip/hip_runtime.h>

typedef unsigned short u16;
typedef __bf16 bfx8 __attribute__((ext_vector_type(8)));
typedef float f32x4 __attribute__((ext_vector_type(4)));
typedef float f32x16 __attribute__((ext_vector_type(16)));

#define MFMA16(a,b,c) __builtin_amdgcn_mfma_f32_16x16x32_bf16(a,b,c,0,0,0)
#define MFMA32(a,b,c) __builtin_amdgcn_mfma_f32_32x32x16_bf16(a,b,c,0,0,0)

// ---------- helpers ----------
__device__ __forceinline__ u16 f2bf(float f) {
  union { float f; unsigned u; } v; v.f = f;
  unsigned r = v.u + 0x7fffu + ((v.u >> 16) & 1u);   // RNE
  return (u16)(r >> 16);
}

__device__ __forceinline__ unsigned cvtpk(float lo, float hi) {
  unsigned r;
  asm("v_cvt_pk_bf16_f32 %0, %1, %2" : "=v"(r) : "v"(lo), "v"(hi));
  return r;
}

// v_permlane32_swap_b32 a, b:
//   a' = {a[0:31], b[0:31]}  (lanes>=32 of a' get b's low lanes)
//   b' = {a[32:63], b[32:63]} (lanes<32 of b' get a's high lanes)
__device__ __forceinline__ void swap32(unsigned &a, unsigned &b) {
  asm("v_permlane32_swap_b32 %0, %1" : "+v"(a), "+v"(b));
}

__device__ __forceinline__ void gld16(const void* g, void* l) {
  __builtin_amdgcn_global_load_lds(
      (const __attribute__((address_space(1))) unsigned int*)g,
      (__attribute__((address_space(3))) unsigned int*)l, 16, 0, 0);
}

// ---------- f32 -> bf16 elementwise (x) ----------
__global__ void convert_bf16_k(const float* __restrict__ in, u16* __restrict__ outp, int nvec) {
  int i = blockIdx.x * 256 + threadIdx.x;
  if (i >= nvec) return;
  float4 v = ((const float4*)in)[i];
  unsigned lo = (unsigned)f2bf(v.x) | ((unsigned)f2bf(v.y) << 16);
  unsigned hi = (unsigned)f2bf(v.z) | ((unsigned)f2bf(v.w) << 16);
  ((uint2*)outp)[i] = make_uint2(lo, hi);
}

// ---------- W [K,N] f32 -> Wt [N,K] bf16 (LDS tile transpose) ----------
__global__ void transpose_k(const float* __restrict__ W, u16* __restrict__ Wt, int K, int N) {
  __shared__ float tile[32][33];
  int n0 = blockIdx.x * 32, k0 = blockIdx.y * 32;
  int tx = threadIdx.x, ty = threadIdx.y;  // (32, 8)
  #pragma unroll
  for (int i = 0; i < 4; i++)
    tile[ty * 4 + i][tx] = W[(size_t)(k0 + ty * 4 + i) * N + n0 + tx];
  __syncthreads();
  #pragma unroll
  for (int i = 0; i < 4; i++)
    Wt[(size_t)(n0 + ty * 4 + i) * K + k0 + tx] = f2bf(tile[tx][ty * 4 + i]);
}

// ---------- bf16 GEMM: C[M,N] f32 = A[M,K] @ Bt[N,K]^T  (m97 structure) ----------
__global__ __launch_bounds__(256) void gemm_bf16(
    const u16* __restrict__ A, const u16* __restrict__ Bt,
    float* __restrict__ C, int M, int N, int K)
{
  __shared__ u16 As[128 * 32];
  __shared__ u16 Bs[128 * 32];
  const int tid = threadIdx.x;
  const int lane = tid & 63, w = tid >> 6;
  const int wm = w >> 1, wn = w & 1;
  const int lrow = lane & 15, lg = lane >> 4, lk = lg * 8;
  const int m0 = blockIdx.y * 128, n0 = blockIdx.x * 128;
  f32x4 acc[4][4] = {};

  const int r0 = tid >> 2, kc = (tid & 3) * 8;
  const u16* Ag = A + (size_t)(m0 + r0) * K + kc;
  const u16* Bg = Bt + (size_t)(n0 + r0) * K + kc;
  u16* Al0 = As + w * 512;
  u16* Al1 = As + 2048 + w * 512;
  u16* Bl0 = Bs + w * 512;
  u16* Bl1 = Bs + 2048 + w * 512;

  for (int k0 = 0; k0 < K; k0 += 32) {
    gld16(Ag + k0, Al0);
    gld16(Ag + (size_t)64 * K + k0, Al1);
    gld16(Bg + k0, Bl0);
    gld16(Bg + (size_t)64 * K + k0, Bl1);
    __syncthreads();
    bfx8 af[4], bff[4];
    #pragma unroll
    for (int i = 0; i < 4; i++) {
      af[i]  = *(const bfx8*)(As + (wm * 64 + i * 16 + lrow) * 32 + lk);
      bff[i] = *(const bfx8*)(Bs + (wn * 64 + i * 16 + lrow) * 32 + lk);
    }
    #pragma unroll
    for (int i = 0; i < 4; i++)
      #pragma unroll
      for (int j = 0; j < 4; j++)
        acc[i][j] = MFMA16(af[i], bff[j], acc[i][j]);
    __syncthreads();
  }
  #pragma unroll
  for (int i = 0; i < 4; i++) {
    int row = m0 + wm * 64 + i * 16 + lg * 4;
    #pragma unroll
    for (int j = 0; j < 4; j++) {
      int col = n0 + wn * 64 + j * 16 + lrow;
      float* cp = C + (size_t)row * N + col;
      #pragma unroll
      for (int r = 0; r < 4; r++) cp[(size_t)r * N] = acc[i][j][r];
    }
  }
}

// ---------- RoPE: Cqkv [4096,3072] f32 -> dst [B,nh,S,64] bf16 ----------
__global__ void rope_k(const float* __restrict__ Cq, const float* __restrict__ cosT,
                       const float* __restrict__ sinT, u16* __restrict__ dst,
                       int nheads, int col_off)
{
  int idx = blockIdx.x * 256 + threadIdx.x;
  int total = 2 * 2048 * nheads * 32;
  if (idx >= total) return;
  int d = idx & 31;
  int h = (idx >> 5) % nheads;
  int sm = idx / (32 * nheads);          // b*2048 + s
  int s = sm & 2047, b = sm >> 11;
  const float* row = Cq + (size_t)sm * 3072 + col_off + h * 64;
  float q1 = row[d], q2 = row[d + 32];
  float c1 = cosT[s * 64 + d], c2 = cosT[s * 64 + d + 32];
  float s1 = sinT[s * 64 + d], s2 = sinT[s * 64 + d + 32];
  float o1 = q1 * c1 - q2 * s1;
  float o2 = q2 * c2 + q1 * s2;
  u16* drow = dst + ((size_t)(b * nheads + h) * 2048 + s) * 64;
  drow[d] = f2bf(o1);
  drow[d + 32] = f2bf(o2);
}

// ---------- V transpose+convert: Cqkv slice -> Vt [B*KV, 64, S] bf16 ----------
__global__ void vtrans_k(const float* __restrict__ Cq, u16* __restrict__ Vt) {
  __shared__ float tile[32][33];
  int s0 = blockIdx.x * 32, d0 = blockIdx.y * 32;
  int bg = blockIdx.z; int b = bg >> 3, g = bg & 7;
  int tx = threadIdx.x, ty = threadIdx.y;  // (32, 8)
  #pragma unroll
  for (int i = 0; i < 4; i++)
    tile[ty * 4 + i][tx] =
        Cq[(size_t)(b * 2048 + s0 + ty * 4 + i) * 3072 + 2560 + g * 64 + d0 + tx];
  __syncthreads();
  #pragma unroll
  for (int i = 0; i < 4; i++)
    Vt[((size_t)(bg * 64 + d0 + ty * 4 + i)) * 2048 + s0 + tx] = f2bf(tile[tx][ty * 4 + i]);
}

// ---------- causal flash attention, GQA — no-LDS, no-barrier main loop ----------
// grid (S/128, H, B), 256 thr. Wave w owns 32 q rows. Swapped operands:
// S^T = K Q^T (col=q), O^T = V^T P^T (col=q) -> softmax fully lane-local.
__global__ __launch_bounds__(256) void attn_k(
    const u16* __restrict__ Qb, const u16* __restrict__ Kb,
    const u16* __restrict__ Vt, u16* __restrict__ Aout)
{
  __shared__ u16 ot[4][32 * 64];   // per-wave epilogue transpose
  const int tid = threadIdx.x, lane = tid & 63, w = tid >> 6;
  const int h = blockIdx.y, b = blockIdx.z;
  const int kvh = h >> 2;
  const int qblk = (int)gridDim.x - 1 - blockIdx.x;   // heavy blocks first
  const int q0 = qblk * 128 + w * 32;
  const int ql = lane & 31, hi = lane >> 5;
  const int qg = q0 + ql;

  const u16* Qp = Qb + (size_t)(b * 32 + h) * 2048 * 64;
  const u16* Kp = Kb + (size_t)(b * 8 + kvh) * 2048 * 64;
  const u16* Vp = Vt + (size_t)(b * 8 + kvh) * 64 * 2048;

  bfx8 qf[4];
  #pragma unroll
  for (int ks = 0; ks < 4; ks++)
    qf[ks] = *(const bfx8*)(Qp + (size_t)(q0 + ql) * 64 + ks * 16 + hi * 8);

  f32x16 oacc0 = {}, oacc1 = {};
  float m2 = -3.0e38f;   // running max, log2 domain
  float lsum = 0.f;
  const float SC = 0.125f * 1.44269504088896f;  // 1/sqrt(64) * log2(e)

  const int nkt = q0 / 64 + 1;
  for (int kt = 0; kt < nkt; kt++) {
    const int kb = kt * 64;
    // ---- S^T = K Q^T : two 32-key tiles ----
    f32x16 st0 = {}, st1 = {};
    #pragma unroll
    for (int ks = 0; ks < 4; ks++) {
      bfx8 kf0 = *(const bfx8*)(Kp + (size_t)(kb + ql) * 64 + ks * 16 + hi * 8);
      bfx8 kf1 = *(const bfx8*)(Kp + (size_t)(kb + 32 + ql) * 64 + ks * 16 + hi * 8);
      st0 = MFMA32(kf0, qf[ks], st0);
      st1 = MFMA32(kf1, qf[ks], st1);
    }
    // ---- scores in log2 domain, causal mask on last tile only ----
    float p[32];
    #pragma unroll
    for (int r = 0; r < 16; r++) { p[r] = st0[r] * SC; p[16 + r] = st1[r] * SC; }
    if (kt == nkt - 1) {
      #pragma unroll
      for (int t = 0; t < 2; t++)
        #pragma unroll
        for (int r = 0; r < 16; r++) {
          int key = kb + t * 32 + (r & 3) + 8 * (r >> 2) + 4 * hi;
          if (key > qg) p[t * 16 + r] = -3.0e38f;
        }
    }
    // ---- lane-local max (+ partner half), defer-max rescale ----
    float tm = p[0];
    #pragma unroll
    for (int i = 1; i < 32; i++) tm = fmaxf(tm, p[i]);
    tm = fmaxf(tm, __shfl_xor(tm, 32));
    float mnew = fmaxf(m2, tm);
    if (!__all(tm <= m2 + 8.0f)) {
      float corr = exp2f(m2 - mnew);
      lsum *= corr;
      #pragma unroll
      for (int i = 0; i < 16; i++) { oacc0[i] *= corr; oacc1[i] *= corr; }
      m2 = mnew;
    }
    float rs = 0.f;
    #pragma unroll
    for (int i = 0; i < 32; i++) { p[i] = exp2f(p[i] - m2); rs += p[i]; }
    lsum += rs;
    // ---- pack P -> bf16 B-fragments (P^T) via cvt_pk + permlane32_swap ----
    bfx8 pb[4];
    #pragma unroll
    for (int ks = 0; ks < 4; ks++) {
      int o = (ks >> 1) * 16 + (ks & 1) * 8;
      unsigned X = cvtpk(p[o + 0], p[o + 1]);
      unsigned Z = cvtpk(p[o + 2], p[o + 3]);
      unsigned Y = cvtpk(p[o + 4], p[o + 5]);
      unsigned W = cvtpk(p[o + 6], p[o + 7]);
      swap32(X, Y);   // X -> word0, Y -> word2
      swap32(Z, W);   // Z -> word1, W -> word3
      union { unsigned u[4]; bfx8 v; } uu;
      uu.u[0] = X; uu.u[1] = Z; uu.u[2] = Y; uu.u[3] = W;
      pb[ks] = uu.v;
    }
    // ---- O^T += V^T P^T ----
    #pragma unroll
    for (int ks = 0; ks < 4; ks++) {
      bfx8 vf0 = *(const bfx8*)(Vp + (size_t)(ql) * 2048 + kb + ks * 16 + hi * 8);
      bfx8 vf1 = *(const bfx8*)(Vp + (size_t)(32 + ql) * 2048 + kb + ks * 16 + hi * 8);
      oacc0 = MFMA32(vf0, pb[ks], oacc0);
      oacc1 = MFMA32(vf1, pb[ks], oacc1);
    }
  }
  // ---- epilogue: normalize, per-wave LDS transpose, coalesced store ----
  lsum += __shfl_xor(lsum, 32);
  float inv = 1.f / lsum;
  u16* my = ot[w];
  #pragma unroll
  for (int dt = 0; dt < 2; dt++) {
    #pragma unroll
    for (int g = 0; g < 4; g++) {
      float a0 = (dt ? oacc1[g*4+0] : oacc0[g*4+0]) * inv;
      float a1 = (dt ? oacc1[g*4+1] : oacc0[g*4+1]) * inv;
      float a2 = (dt ? oacc1[g*4+2] : oacc0[g*4+2]) * inv;
      float a3 = (dt ? oacc1[g*4+3] : oacc0[g*4+3]) * inv;
      unsigned w0 = cvtpk(a0, a1), w1 = cvtpk(a2, a3);
      int d = dt * 32 + g * 8 + 4 * hi;
      int byte = (ql * 128 + d * 2) ^ ((ql & 7) << 4);
      *(uint2*)((char*)my + byte) = make_uint2(w0, w1);
    }
  }
  // wave-local LDS: no barrier needed (compiler inserts lgkmcnt)
  #pragma unroll
  for (int rr = 0; rr < 4; rr++) {
    int q = rr * 8 + (lane >> 3);
    int dk = (lane & 7) * 8;
    int byte = (q * 128 + dk * 2) ^ ((q & 7) << 4);
    uint4 val = *(uint4*)((char*)my + byte);
    *(uint4*)(Aout + ((size_t)(b * 2048) + q0 + q) * 2048 + h * 64 + dk) = val;
  }
}

// ---------- launch ----------
extern "C" void kernel_launch(void* const* d_in, const int* in_sizes, int n_in,
                              void* d_out, int out_size, void* d_ws, size_t ws_size,
                              hipStream_t stream) {
  const float* x    = (const float*)d_in[0];
  const float* cosT = (const float*)d_in[1];
  const float* sinT = (const float*)d_in[2];
  const float* Wq   = (const float*)d_in[3];
  const float* Wk   = (const float*)d_in[4];
  const float* Wv   = (const float*)d_in[5];
  const float* Wo   = (const float*)d_in[6];
  float* out = (float*)d_out;
  char* ws = (char*)d_ws;

  // workspace layout (aliased; total 88,080,384 B)
  u16* xb    = (u16*)(ws);                          // 16 MB
  u16* WqkvT = (u16*)(ws + 16777216);               // 12 MB
  u16* Qb    = (u16*)(ws);                          // alias over xb (16 MB)
  u16* Kb    = (u16*)(ws + 16777216);               // alias over WqkvT (4 MB)
  u16* Vt    = (u16*)(ws + 16777216 + 4194304);     // alias over WqkvT (4 MB)
  u16* WoT   = (u16*)(ws + 29360128);               // 8 MB
  float* Cqkv = (float*)(ws + 37748736);            // 48 MB
  u16* Aout  = (u16*)(ws + 37748736);               // alias over dead Cqkv

  dim3 tb(32, 8);
  convert_bf16_k<<<8192, 256, 0, stream>>>(x, xb, 2097152);
  transpose_k<<<dim3(64, 64), tb, 0, stream>>>(Wq, WqkvT, 2048, 2048);
  transpose_k<<<dim3(16, 64), tb, 0, stream>>>(Wk, WqkvT + (size_t)2048 * 2048, 2048, 512);
  transpose_k<<<dim3(16, 64), tb, 0, stream>>>(Wv, WqkvT + (size_t)2560 * 2048, 2048, 512);
  transpose_k<<<dim3(64, 64), tb, 0, stream>>>(Wo, WoT, 2048, 2048);

  gemm_bf16<<<dim3(24, 32), 256, 0, stream>>>(xb, WqkvT, Cqkv, 4096, 3072, 2048);

  rope_k<<<16384, 256, 0, stream>>>(Cqkv, cosT, sinT, Qb, 32, 0);
  rope_k<<<4096, 256, 0, stream>>>(Cqkv, cosT, sinT, Kb, 8, 2048);
  vtrans_k<<<dim3(64, 2, 16), tb, 0, stream>>>(Cqkv, Vt);

  attn_k<<<dim3(16, 32, 2), 256, 0, stream>>>(Qb, Kb, Vt, Aout);

  gemm_bf16<<<dim3(16, 32), 256, 0, stream>>>(Aout, WoT, out, 4096, 2048, 2048);
}

// Round 3
// 297.610 us; speedup vs baseline: 1.8795x; 1.3746x over previous
//
#include <hip/hip_runtime.h>

typedef unsigned short u16;
typedef __bf16 bfx8 __attribute__((ext_vector_type(8)));
typedef float f32x4 __attribute__((ext_vector_type(4)));
typedef float f32x16 __attribute__((ext_vector_type(16)));

#define MFMA16(a,b,c) __builtin_amdgcn_mfma_f32_16x16x32_bf16(a,b,c,0,0,0)
#define MFMA32(a,b,c) __builtin_amdgcn_mfma_f32_32x32x16_bf16(a,b,c,0,0,0)

// ---------- helpers ----------
__device__ __forceinline__ u16 f2bf(float f) {
  union { float f; unsigned u; } v; v.f = f;
  unsigned r = v.u + 0x7fffu + ((v.u >> 16) & 1u);   // RNE
  return (u16)(r >> 16);
}

__device__ __forceinline__ unsigned cvtpk(float lo, float hi) {
  unsigned r;
  asm("v_cvt_pk_bf16_f32 %0, %1, %2" : "=v"(r) : "v"(lo), "v"(hi));
  return r;
}

__device__ __forceinline__ void swap32(unsigned &a, unsigned &b) {
  asm("v_permlane32_swap_b32 %0, %1" : "+v"(a), "+v"(b));
}

__device__ __forceinline__ void gld16(const void* g, void* l) {
  __builtin_amdgcn_global_load_lds(
      (const __attribute__((address_space(1))) unsigned int*)g,
      (__attribute__((address_space(3))) unsigned int*)l, 16, 0, 0);
}

// ---------- f32 -> bf16 elementwise (x) ----------
__global__ void convert_bf16_k(const float* __restrict__ in, u16* __restrict__ outp, int nvec) {
  int i = blockIdx.x * 256 + threadIdx.x;
  if (i >= nvec) return;
  float4 v = ((const float4*)in)[i];
  unsigned lo = (unsigned)f2bf(v.x) | ((unsigned)f2bf(v.y) << 16);
  unsigned hi = (unsigned)f2bf(v.z) | ((unsigned)f2bf(v.w) << 16);
  ((uint2*)outp)[i] = make_uint2(lo, hi);
}

// ---------- W [K,N] f32 -> Wt [N,K] bf16 (LDS tile transpose) ----------
__global__ void transpose_k(const float* __restrict__ W, u16* __restrict__ Wt, int K, int N) {
  __shared__ float tile[32][33];
  int n0 = blockIdx.x * 32, k0 = blockIdx.y * 32;
  int tx = threadIdx.x, ty = threadIdx.y;  // (32, 8)
  #pragma unroll
  for (int i = 0; i < 4; i++)
    tile[ty * 4 + i][tx] = W[(size_t)(k0 + ty * 4 + i) * N + n0 + tx];
  __syncthreads();
  #pragma unroll
  for (int i = 0; i < 4; i++)
    Wt[(size_t)(n0 + ty * 4 + i) * K + k0 + tx] = f2bf(tile[tx][ty * 4 + i]);
}

// ---------- bf16 GEMM: C[M,N] f32 = A[M,K] @ Bt[N,K]^T  (m97 structure) ----------
__global__ __launch_bounds__(256) void gemm_bf16(
    const u16* __restrict__ A, const u16* __restrict__ Bt,
    float* __restrict__ C, int M, int N, int K)
{
  __shared__ u16 As[128 * 32];
  __shared__ u16 Bs[128 * 32];
  const int tid = threadIdx.x;
  const int lane = tid & 63, w = tid >> 6;
  const int wm = w >> 1, wn = w & 1;
  const int lrow = lane & 15, lg = lane >> 4, lk = lg * 8;
  const int m0 = blockIdx.y * 128, n0 = blockIdx.x * 128;
  f32x4 acc[4][4] = {};

  const int r0 = tid >> 2, kc = (tid & 3) * 8;
  const u16* Ag = A + (size_t)(m0 + r0) * K + kc;
  const u16* Bg = Bt + (size_t)(n0 + r0) * K + kc;
  u16* Al0 = As + w * 512;
  u16* Al1 = As + 2048 + w * 512;
  u16* Bl0 = Bs + w * 512;
  u16* Bl1 = Bs + 2048 + w * 512;

  for (int k0 = 0; k0 < K; k0 += 32) {
    gld16(Ag + k0, Al0);
    gld16(Ag + (size_t)64 * K + k0, Al1);
    gld16(Bg + k0, Bl0);
    gld16(Bg + (size_t)64 * K + k0, Bl1);
    __syncthreads();
    bfx8 af[4], bff[4];
    #pragma unroll
    for (int i = 0; i < 4; i++) {
      af[i]  = *(const bfx8*)(As + (wm * 64 + i * 16 + lrow) * 32 + lk);
      bff[i] = *(const bfx8*)(Bs + (wn * 64 + i * 16 + lrow) * 32 + lk);
    }
    #pragma unroll
    for (int i = 0; i < 4; i++)
      #pragma unroll
      for (int j = 0; j < 4; j++)
        acc[i][j] = MFMA16(af[i], bff[j], acc[i][j]);
    __syncthreads();
  }
  #pragma unroll
  for (int i = 0; i < 4; i++) {
    int row = m0 + wm * 64 + i * 16 + lg * 4;
    #pragma unroll
    for (int j = 0; j < 4; j++) {
      int col = n0 + wn * 64 + j * 16 + lrow;
      float* cp = C + (size_t)row * N + col;
      #pragma unroll
      for (int r = 0; r < 4; r++) cp[(size_t)r * N] = acc[i][j][r];
    }
  }
}

// ---------- RoPE: Cqkv [4096,3072] f32 -> dst [B,nh,S,64] bf16 ----------
__global__ void rope_k(const float* __restrict__ Cq, const float* __restrict__ cosT,
                       const float* __restrict__ sinT, u16* __restrict__ dst,
                       int nheads, int col_off)
{
  int idx = blockIdx.x * 256 + threadIdx.x;
  int total = 2 * 2048 * nheads * 32;
  if (idx >= total) return;
  int d = idx & 31;
  int h = (idx >> 5) % nheads;
  int sm = idx / (32 * nheads);          // b*2048 + s
  int s = sm & 2047, b = sm >> 11;
  const float* row = Cq + (size_t)sm * 3072 + col_off + h * 64;
  float q1 = row[d], q2 = row[d + 32];
  float c1 = cosT[s * 64 + d], c2 = cosT[s * 64 + d + 32];
  float s1 = sinT[s * 64 + d], s2 = sinT[s * 64 + d + 32];
  float o1 = q1 * c1 - q2 * s1;
  float o2 = q2 * c2 + q1 * s2;
  u16* drow = dst + ((size_t)(b * nheads + h) * 2048 + s) * 64;
  drow[d] = f2bf(o1);
  drow[d + 32] = f2bf(o2);
}

// ---------- V transpose+convert: Cqkv slice -> Vt [B*KV, 64, S] bf16 ----------
__global__ void vtrans_k(const float* __restrict__ Cq, u16* __restrict__ Vt) {
  __shared__ float tile[32][33];
  int s0 = blockIdx.x * 32, d0 = blockIdx.y * 32;
  int bg = blockIdx.z; int b = bg >> 3, g = bg & 7;
  int tx = threadIdx.x, ty = threadIdx.y;  // (32, 8)
  #pragma unroll
  for (int i = 0; i < 4; i++)
    tile[ty * 4 + i][tx] =
        Cq[(size_t)(b * 2048 + s0 + ty * 4 + i) * 3072 + 2560 + g * 64 + d0 + tx];
  __syncthreads();
  #pragma unroll
  for (int i = 0; i < 4; i++)
    Vt[((size_t)(bg * 64 + d0 + ty * 4 + i)) * 2048 + s0 + tx] = f2bf(tile[tx][ty * 4 + i]);
}

// ---------- causal flash attention, GQA — balanced pairs + in-wave pipeline ----------
// grid (8, H, B), 256 thr. Wave w handles q-tiles {63-(bx*4+w), bx*4+w} (32 rows
// each) for head h: every wave = exactly 33 K-tiles -> flat occupancy, no tail.
// Swapped operands: S^T = K Q^T, O^T = V^T P^T -> softmax lane-local.
__global__ __launch_bounds__(256, 2) void attn_k(
    const u16* __restrict__ Qb, const u16* __restrict__ Kb,
    const u16* __restrict__ Vt, u16* __restrict__ Aout)
{
  __shared__ u16 ot[4][32 * 64];   // per-wave epilogue transpose
  const int tid = threadIdx.x, lane = tid & 63, w = tid >> 6;
  const int h = blockIdx.y, b = blockIdx.z;
  const int kvh = h >> 2;
  const int ql = lane & 31, hi = lane >> 5;
  const int qrA = blockIdx.x * 4 + w;     // in [0,32)

  const u16* Qp = Qb + (size_t)(b * 32 + h) * 2048 * 64;
  const u16* Kp = Kb + (size_t)(b * 8 + kvh) * 2048 * 64;
  const u16* Vp = Vt + (size_t)(b * 8 + kvh) * 64 * 2048;
  const float SC = 0.125f * 1.44269504088896f;  // 1/sqrt(64) * log2(e)

  #pragma unroll
  for (int half = 0; half < 2; half++) {
    const int qr = half ? qrA : 63 - qrA;   // heavy tile first
    const int q0 = qr * 32;
    const int qg = q0 + ql;
    const int nkt = qr / 2 + 1;

    bfx8 qf[4];
    #pragma unroll
    for (int ks = 0; ks < 4; ks++)
      qf[ks] = *(const bfx8*)(Qp + (size_t)(q0 + ql) * 64 + ks * 16 + hi * 8);

    f32x16 oacc0 = {}, oacc1 = {};
    float m2 = -3.0e38f;
    float lsum = 0.f;

    // prefetch K-tile 0
    bfx8 ka[8];
    #pragma unroll
    for (int ks = 0; ks < 4; ks++) {
      ka[ks]     = *(const bfx8*)(Kp + (size_t)(ql) * 64 + ks * 16 + hi * 8);
      ka[4 + ks] = *(const bfx8*)(Kp + (size_t)(32 + ql) * 64 + ks * 16 + hi * 8);
    }

    for (int kt = 0; kt < nkt; kt++) {
      const int kb = kt * 64;
      // issue V loads for this tile (consumed after softmax)
      bfx8 va[8];
      #pragma unroll
      for (int ks = 0; ks < 4; ks++) {
        va[ks]     = *(const bfx8*)(Vp + (size_t)(ql) * 2048 + kb + ks * 16 + hi * 8);
        va[4 + ks] = *(const bfx8*)(Vp + (size_t)(32 + ql) * 2048 + kb + ks * 16 + hi * 8);
      }
      // S^T = K Q^T from prefetched ka
      f32x16 st0 = {}, st1 = {};
      #pragma unroll
      for (int ks = 0; ks < 4; ks++) {
        st0 = MFMA32(ka[ks], qf[ks], st0);
        st1 = MFMA32(ka[4 + ks], qf[ks], st1);
      }
      // issue K loads for next tile (consumed next iteration)
      const int kbn = (kt + 1 < nkt) ? kb + 64 : 0;
      bfx8 kn[8];
      #pragma unroll
      for (int ks = 0; ks < 4; ks++) {
        kn[ks]     = *(const bfx8*)(Kp + (size_t)(kbn + ql) * 64 + ks * 16 + hi * 8);
        kn[4 + ks] = *(const bfx8*)(Kp + (size_t)(kbn + 32 + ql) * 64 + ks * 16 + hi * 8);
      }
      // scale (+ causal mask on last tile), in place
      #pragma unroll
      for (int r = 0; r < 16; r++) { st0[r] *= SC; st1[r] *= SC; }
      if (kt == nkt - 1) {
        #pragma unroll
        for (int r = 0; r < 16; r++) {
          int crow = (r & 3) + 8 * (r >> 2) + 4 * hi;
          if (kb + crow > qg) st0[r] = -3.0e38f;
          if (kb + 32 + crow > qg) st1[r] = -3.0e38f;
        }
      }
      // lane-local max (+ partner half), defer-max rescale
      float tm = st0[0];
      #pragma unroll
      for (int r = 1; r < 16; r++) tm = fmaxf(tm, st0[r]);
      #pragma unroll
      for (int r = 0; r < 16; r++) tm = fmaxf(tm, st1[r]);
      tm = fmaxf(tm, __shfl_xor(tm, 32));
      float mnew = fmaxf(m2, tm);
      if (!__all(tm <= m2 + 8.0f)) {
        float corr = exp2f(m2 - mnew);
        lsum *= corr;
        #pragma unroll
        for (int i = 0; i < 16; i++) { oacc0[i] *= corr; oacc1[i] *= corr; }
        m2 = mnew;
      }
      float rs = 0.f;
      #pragma unroll
      for (int r = 0; r < 16; r++) { st0[r] = exp2f(st0[r] - m2); rs += st0[r]; }
      #pragma unroll
      for (int r = 0; r < 16; r++) { st1[r] = exp2f(st1[r] - m2); rs += st1[r]; }
      lsum += rs;
      // pack P -> bf16 B-fragments (P^T) via cvt_pk + permlane32_swap
      bfx8 pb[4];
      #pragma unroll
      for (int ks = 0; ks < 4; ks++) {
        int o = (ks & 1) * 8;
        unsigned X = cvtpk(ks < 2 ? st0[o + 0] : st1[o + 0], ks < 2 ? st0[o + 1] : st1[o + 1]);
        unsigned Z = cvtpk(ks < 2 ? st0[o + 2] : st1[o + 2], ks < 2 ? st0[o + 3] : st1[o + 3]);
        unsigned Y = cvtpk(ks < 2 ? st0[o + 4] : st1[o + 4], ks < 2 ? st0[o + 5] : st1[o + 5]);
        unsigned W = cvtpk(ks < 2 ? st0[o + 6] : st1[o + 6], ks < 2 ? st0[o + 7] : st1[o + 7]);
        swap32(X, Y);
        swap32(Z, W);
        union { unsigned u[4]; bfx8 v; } uu;
        uu.u[0] = X; uu.u[1] = Z; uu.u[2] = Y; uu.u[3] = W;
        pb[ks] = uu.v;
      }
      // O^T += V^T P^T
      #pragma unroll
      for (int ks = 0; ks < 4; ks++) {
        oacc0 = MFMA32(va[ks], pb[ks], oacc0);
        oacc1 = MFMA32(va[4 + ks], pb[ks], oacc1);
      }
      #pragma unroll
      for (int i = 0; i < 8; i++) ka[i] = kn[i];
    }
    // epilogue: normalize, per-wave LDS transpose, coalesced store
    lsum += __shfl_xor(lsum, 32);
    float inv = 1.f / lsum;
    u16* my = ot[w];
    #pragma unroll
    for (int dt = 0; dt < 2; dt++) {
      #pragma unroll
      for (int g = 0; g < 4; g++) {
        float a0 = (dt ? oacc1[g*4+0] : oacc0[g*4+0]) * inv;
        float a1 = (dt ? oacc1[g*4+1] : oacc0[g*4+1]) * inv;
        float a2 = (dt ? oacc1[g*4+2] : oacc0[g*4+2]) * inv;
        float a3 = (dt ? oacc1[g*4+3] : oacc0[g*4+3]) * inv;
        unsigned w0 = cvtpk(a0, a1), w1 = cvtpk(a2, a3);
        int d = dt * 32 + g * 8 + 4 * hi;
        int byte = (ql * 128 + d * 2) ^ ((ql & 7) << 4);
        *(uint2*)((char*)my + byte) = make_uint2(w0, w1);
      }
    }
    #pragma unroll
    for (int rr = 0; rr < 4; rr++) {
      int q = rr * 8 + (lane >> 3);
      int dk = (lane & 7) * 8;
      int byte = (q * 128 + dk * 2) ^ ((q & 7) << 4);
      uint4 val = *(uint4*)((char*)my + byte);
      *(uint4*)(Aout + ((size_t)(b * 2048) + q0 + q) * 2048 + h * 64 + dk) = val;
    }
  }
}

// ---------- launch ----------
extern "C" void kernel_launch(void* const* d_in, const int* in_sizes, int n_in,
                              void* d_out, int out_size, void* d_ws, size_t ws_size,
                              hipStream_t stream) {
  const float* x    = (const float*)d_in[0];
  const float* cosT = (const float*)d_in[1];
  const float* sinT = (const float*)d_in[2];
  const float* Wq   = (const float*)d_in[3];
  const float* Wk   = (const float*)d_in[4];
  const float* Wv   = (const float*)d_in[5];
  const float* Wo   = (const float*)d_in[6];
  float* out = (float*)d_out;
  char* ws = (char*)d_ws;

  // workspace layout (aliased; total 88,080,384 B)
  u16* xb    = (u16*)(ws);                          // 16 MB
  u16* WqkvT = (u16*)(ws + 16777216);               // 12 MB
  u16* Qb    = (u16*)(ws);                          // alias over xb (16 MB)
  u16* Kb    = (u16*)(ws + 16777216);               // alias over WqkvT (4 MB)
  u16* Vt    = (u16*)(ws + 16777216 + 4194304);     // alias over WqkvT (4 MB)
  u16* WoT   = (u16*)(ws + 29360128);               // 8 MB
  float* Cqkv = (float*)(ws + 37748736);            // 48 MB
  u16* Aout  = (u16*)(ws + 37748736);               // alias over dead Cqkv

  dim3 tb(32, 8);
  convert_bf16_k<<<8192, 256, 0, stream>>>(x, xb, 2097152);
  transpose_k<<<dim3(64, 64), tb, 0, stream>>>(Wq, WqkvT, 2048, 2048);
  transpose_k<<<dim3(16, 64), tb, 0, stream>>>(Wk, WqkvT + (size_t)2048 * 2048, 2048, 512);
  transpose_k<<<dim3(16, 64), tb, 0, stream>>>(Wv, WqkvT + (size_t)2560 * 2048, 2048, 512);
  transpose_k<<<dim3(64, 64), tb, 0, stream>>>(Wo, WoT, 2048, 2048);

  gemm_bf16<<<dim3(24, 32), 256, 0, stream>>>(xb, WqkvT, Cqkv, 4096, 3072, 2048);

  rope_k<<<16384, 256, 0, stream>>>(Cqkv, cosT, sinT, Qb, 32, 0);
  rope_k<<<4096, 256, 0, stream>>>(Cqkv, cosT, sinT, Kb, 8, 2048);
  vtrans_k<<<dim3(64, 2, 16), tb, 0, stream>>>(Cqkv, Vt);

  attn_k<<<dim3(8, 32, 2), 256, 0, stream>>>(Qb, Kb, Vt, Aout);

  gemm_bf16<<<dim3(16, 32), 256, 0, stream>>>(Aout, WoT, out, 4096, 2048, 2048);
}

// Round 4
// 283.163 us; speedup vs baseline: 1.9754x; 1.0510x over previous
//
#include <hip/hip_runtime.h>

typedef unsigned short u16;
typedef __bf16 bfx8 __attribute__((ext_vector_type(8)));
typedef float f32x4 __attribute__((ext_vector_type(4)));
typedef float f32x16 __attribute__((ext_vector_type(16)));

#define MFMA16(a,b,c) __builtin_amdgcn_mfma_f32_16x16x32_bf16(a,b,c,0,0,0)
#define MFMA32(a,b,c) __builtin_amdgcn_mfma_f32_32x32x16_bf16(a,b,c,0,0,0)

// ---------- helpers ----------
__device__ __forceinline__ u16 f2bf(float f) {
  union { float f; unsigned u; } v; v.f = f;
  unsigned r = v.u + 0x7fffu + ((v.u >> 16) & 1u);   // RNE
  return (u16)(r >> 16);
}

__device__ __forceinline__ unsigned cvtpk(float lo, float hi) {
  unsigned r;
  asm("v_cvt_pk_bf16_f32 %0, %1, %2" : "=v"(r) : "v"(lo), "v"(hi));
  return r;
}

__device__ __forceinline__ void swap32(unsigned &a, unsigned &b) {
  asm("v_permlane32_swap_b32 %0, %1" : "+v"(a), "+v"(b));
}

__device__ __forceinline__ void gld16(const void* g, void* l) {
  __builtin_amdgcn_global_load_lds(
      (const __attribute__((address_space(1))) unsigned int*)g,
      (__attribute__((address_space(3))) unsigned int*)l, 16, 0, 0);
}

// ---------- f32 -> bf16 elementwise (x) ----------
__global__ void convert_bf16_k(const float* __restrict__ in, u16* __restrict__ outp, int nvec) {
  int i = blockIdx.x * 256 + threadIdx.x;
  if (i >= nvec) return;
  float4 v = ((const float4*)in)[i];
  unsigned lo = (unsigned)f2bf(v.x) | ((unsigned)f2bf(v.y) << 16);
  unsigned hi = (unsigned)f2bf(v.z) | ((unsigned)f2bf(v.w) << 16);
  ((uint2*)outp)[i] = make_uint2(lo, hi);
}

// ---------- W [K,N] f32 -> Wt [N,K] bf16 (LDS tile transpose) ----------
__global__ void transpose_k(const float* __restrict__ W, u16* __restrict__ Wt, int K, int N) {
  __shared__ float tile[32][33];
  int n0 = blockIdx.x * 32, k0 = blockIdx.y * 32;
  int tx = threadIdx.x, ty = threadIdx.y;  // (32, 8)
  #pragma unroll
  for (int i = 0; i < 4; i++)
    tile[ty * 4 + i][tx] = W[(size_t)(k0 + ty * 4 + i) * N + n0 + tx];
  __syncthreads();
  #pragma unroll
  for (int i = 0; i < 4; i++)
    Wt[(size_t)(n0 + ty * 4 + i) * K + k0 + tx] = f2bf(tile[tx][ty * 4 + i]);
}

// ---------- bf16 GEMM: C[M,N] f32 = A[M,K] @ Bt[N,K]^T  (m97 structure, XCD swizzle) ----------
__global__ __launch_bounds__(256) void gemm_bf16(
    const u16* __restrict__ A, const u16* __restrict__ Bt,
    float* __restrict__ C, int M, int N, int K)
{
  __shared__ u16 As[128 * 32];
  __shared__ u16 Bs[128 * 32];
  const int tid = threadIdx.x;
  const int lane = tid & 63, w = tid >> 6;
  const int wm = w >> 1, wn = w & 1;
  const int lrow = lane & 15, lg = lane >> 4, lk = lg * 8;
  // bijective XCD swizzle (nwg % 8 == 0 for both our grids)
  const int nwg = gridDim.x * gridDim.y;
  const int bid = blockIdx.y * gridDim.x + blockIdx.x;
  const int per = nwg >> 3;
  const int swz = (bid & 7) * per + (bid >> 3);
  const int m0 = (swz / gridDim.x) * 128, n0 = (swz % gridDim.x) * 128;
  f32x4 acc[4][4] = {};

  const int r0 = tid >> 2, kc = (tid & 3) * 8;
  const u16* Ag = A + (size_t)(m0 + r0) * K + kc;
  const u16* Bg = Bt + (size_t)(n0 + r0) * K + kc;
  u16* Al0 = As + w * 512;
  u16* Al1 = As + 2048 + w * 512;
  u16* Bl0 = Bs + w * 512;
  u16* Bl1 = Bs + 2048 + w * 512;

  for (int k0 = 0; k0 < K; k0 += 32) {
    gld16(Ag + k0, Al0);
    gld16(Ag + (size_t)64 * K + k0, Al1);
    gld16(Bg + k0, Bl0);
    gld16(Bg + (size_t)64 * K + k0, Bl1);
    __syncthreads();
    bfx8 af[4], bff[4];
    #pragma unroll
    for (int i = 0; i < 4; i++) {
      af[i]  = *(const bfx8*)(As + (wm * 64 + i * 16 + lrow) * 32 + lk);
      bff[i] = *(const bfx8*)(Bs + (wn * 64 + i * 16 + lrow) * 32 + lk);
    }
    #pragma unroll
    for (int i = 0; i < 4; i++)
      #pragma unroll
      for (int j = 0; j < 4; j++)
        acc[i][j] = MFMA16(af[i], bff[j], acc[i][j]);
    __syncthreads();
  }
  #pragma unroll
  for (int i = 0; i < 4; i++) {
    int row = m0 + wm * 64 + i * 16 + lg * 4;
    #pragma unroll
    for (int j = 0; j < 4; j++) {
      int col = n0 + wn * 64 + j * 16 + lrow;
      float* cp = C + (size_t)row * N + col;
      #pragma unroll
      for (int r = 0; r < 4; r++) cp[(size_t)r * N] = acc[i][j][r];
    }
  }
}

// ---------- RoPE -> fragment-linear Q/K ----------
// Frag layout per (b,head): regions of 2048 els per 32-row s-tile; within:
// chunk(ks, l) at (ks*64 + l)*8, holding rows s = qt*32 + (l&31),
// d = ks*16 + (l>>5)*8 .. +8.  Thread t=(sm*nh + h)*4 + pc handles d0=pc*8
// (chunk ks=pc>>1, hi=pc&1) + partner d0+32 (ks+2).
__global__ void rope_frag_k(const float* __restrict__ Cq, const float* __restrict__ cosT,
                            const float* __restrict__ sinT, u16* __restrict__ dst,
                            int col_off, int lgnh)
{
  int t = blockIdx.x * 256 + threadIdx.x;
  int pc = t & 3;
  int h = (t >> 2) & ((1 << lgnh) - 1);
  int sm = t >> (2 + lgnh);               // b*2048 + s
  int s = sm & 2047, b = sm >> 11;
  int d0 = pc * 8;
  const float* row = Cq + (size_t)sm * 3072 + col_off + h * 64;
  float4 aA = *(const float4*)(row + d0);
  float4 aB = *(const float4*)(row + d0 + 4);
  float4 cA = *(const float4*)(row + d0 + 32);
  float4 cB = *(const float4*)(row + d0 + 36);
  const float* cr = cosT + s * 64;
  const float* sr = sinT + s * 64;
  float4 c1A = *(const float4*)(cr + d0),      c1B = *(const float4*)(cr + d0 + 4);
  float4 c2A = *(const float4*)(cr + d0 + 32), c2B = *(const float4*)(cr + d0 + 36);
  float4 s1A = *(const float4*)(sr + d0),      s1B = *(const float4*)(sr + d0 + 4);
  float4 s2A = *(const float4*)(sr + d0 + 32), s2B = *(const float4*)(sr + d0 + 36);
  float av[8] = {aA.x,aA.y,aA.z,aA.w,aB.x,aB.y,aB.z,aB.w};
  float cv[8] = {cA.x,cA.y,cA.z,cA.w,cB.x,cB.y,cB.z,cB.w};
  float c1[8] = {c1A.x,c1A.y,c1A.z,c1A.w,c1B.x,c1B.y,c1B.z,c1B.w};
  float c2[8] = {c2A.x,c2A.y,c2A.z,c2A.w,c2B.x,c2B.y,c2B.z,c2B.w};
  float s1[8] = {s1A.x,s1A.y,s1A.z,s1A.w,s1B.x,s1B.y,s1B.z,s1B.w};
  float s2[8] = {s2A.x,s2A.y,s2A.z,s2A.w,s2B.x,s2B.y,s2B.z,s2B.w};
  union { u16 h[8]; uint4 u; } o1, o2;
  #pragma unroll
  for (int j = 0; j < 8; j++) {
    o1.h[j] = f2bf(av[j] * c1[j] - cv[j] * s1[j]);
    o2.h[j] = f2bf(cv[j] * c2[j] + av[j] * s2[j]);
  }
  int qt = s >> 5, ql = s & 31;
  int ks = pc >> 1, hi = pc & 1;
  u16* base = dst + ((size_t)((b << lgnh) + h) * 64 + qt) * 2048;
  int loff = (hi * 32 + ql) * 8;
  *(uint4*)(base + ks * 512 + loff) = o1.u;
  *(uint4*)(base + (ks + 2) * 512 + loff) = o2.u;
}

// ---------- V -> fragment-linear V^T ----------
// Chunk(kt, sub, ks, l) at ((kt*8 + sub*4 + ks)*64 + l)*8 holds
// d = sub*32 + (l&31), s = kt*64 + ks*16 + (l>>5)*8 .. +8.
__global__ void vtrans_k(const float* __restrict__ Cq, u16* __restrict__ Vf) {
  __shared__ float tile[64][64];
  int kt = blockIdx.x;                 // 32 s-tiles of 64
  int bg = blockIdx.y; int b = bg >> 3, g = bg & 7;
  int tid = threadIdx.x;
  const float* src = Cq + (size_t)(b * 2048 + kt * 64) * 3072 + 2560 + g * 64;
  int rr = tid >> 4, c4 = (tid & 15) * 4;
  #pragma unroll
  for (int p = 0; p < 4; p++) {
    int r = p * 16 + rr;
    *(float4*)&tile[r][c4] = *(const float4*)(src + (size_t)r * 3072 + c4);
  }
  __syncthreads();
  u16* dst = Vf + (size_t)(bg * 32 + kt) * 4096;
  #pragma unroll
  for (int cc = 0; cc < 2; cc++) {
    int cid = tid * 2 + cc;
    int l = cid & 63, ks = (cid >> 6) & 3, sub = cid >> 8;
    int d = sub * 32 + (l & 31);
    int s0 = ks * 16 + (l >> 5) * 8;
    union { u16 h[8]; uint4 u; } o;
    #pragma unroll
    for (int j = 0; j < 8; j++) o.h[j] = f2bf(tile[s0 + j][d]);
    *(uint4*)(dst + cid * 8) = o.u;
  }
}

// ---------- causal flash attention, GQA — fragment-linear, coalesced ----------
// grid (16, H, B), 256 thr. Wave w owns q-tile qr=(15-bx)*4+w (heavy first).
// Swapped operands: S^T = K Q^T, O^T = V^T P^T -> softmax lane-local.
__global__ __launch_bounds__(256, 3) void attn_k(
    const u16* __restrict__ Qf, const u16* __restrict__ Kf,
    const u16* __restrict__ Vf, u16* __restrict__ Aout)
{
  __shared__ u16 ot[4][32 * 64];   // per-wave epilogue transpose
  const int tid = threadIdx.x, lane = tid & 63, w = tid >> 6;
  const int h = blockIdx.y, b = blockIdx.z;
  const int kvh = h >> 2;
  const int ql = lane & 31, hi = lane >> 5;
  const int qr = (15 - (int)blockIdx.x) * 4 + w;   // in [0,64)
  const int q0 = qr * 32;
  const int qg = q0 + ql;
  const int nkt = qr / 2 + 1;

  const u16* Qp = Qf + ((size_t)(b * 32 + h) * 64 + qr) * 2048;
  const u16* Kp = Kf + (size_t)(b * 8 + kvh) * 131072;
  const u16* Vp = Vf + (size_t)(b * 8 + kvh) * 131072;
  const float SC = 0.125f * 1.44269504088896f;  // 1/sqrt(64) * log2(e)

  bfx8 qf[4];
  #pragma unroll
  for (int ks = 0; ks < 4; ks++)
    qf[ks] = *(const bfx8*)(Qp + ks * 512 + lane * 8);

  f32x16 oacc0 = {}, oacc1 = {};
  float m2 = -3.0e38f;
  float lsum = 0.f;

  // prefetch K-tile 0 (coalesced: 64 lanes x 16B consecutive)
  bfx8 ka[8];
  #pragma unroll
  for (int i = 0; i < 8; i++)
    ka[i] = *(const bfx8*)(Kp + i * 512 + lane * 8);

  for (int kt = 0; kt < nkt; kt++) {
    const int kb = kt * 64;
    // V loads for this tile (consumed after softmax)
    bfx8 va[8];
    #pragma unroll
    for (int i = 0; i < 8; i++)
      va[i] = *(const bfx8*)(Vp + (size_t)kt * 4096 + i * 512 + lane * 8);
    // S^T = K Q^T from prefetched ka
    f32x16 st0 = {}, st1 = {};
    #pragma unroll
    for (int ks = 0; ks < 4; ks++) {
      st0 = MFMA32(ka[ks], qf[ks], st0);
      st1 = MFMA32(ka[4 + ks], qf[ks], st1);
    }
    // K loads for next tile
    const int ktn = (kt + 1 < nkt) ? kt + 1 : 0;
    bfx8 kn[8];
    #pragma unroll
    for (int i = 0; i < 8; i++)
      kn[i] = *(const bfx8*)(Kp + (size_t)ktn * 4096 + i * 512 + lane * 8);
    // scale (+ causal mask on last tile), in place
    #pragma unroll
    for (int r = 0; r < 16; r++) { st0[r] *= SC; st1[r] *= SC; }
    if (kt == nkt - 1) {
      #pragma unroll
      for (int r = 0; r < 16; r++) {
        int crow = (r & 3) + 8 * (r >> 2) + 4 * hi;
        if (kb + crow > qg) st0[r] = -3.0e38f;
        if (kb + 32 + crow > qg) st1[r] = -3.0e38f;
      }
    }
    // lane-local max (+ partner half), defer-max rescale
    float tm = st0[0];
    #pragma unroll
    for (int r = 1; r < 16; r++) tm = fmaxf(tm, st0[r]);
    #pragma unroll
    for (int r = 0; r < 16; r++) tm = fmaxf(tm, st1[r]);
    tm = fmaxf(tm, __shfl_xor(tm, 32));
    float mnew = fmaxf(m2, tm);
    if (!__all(tm <= m2 + 8.0f)) {
      float corr = exp2f(m2 - mnew);
      lsum *= corr;
      #pragma unroll
      for (int i = 0; i < 16; i++) { oacc0[i] *= corr; oacc1[i] *= corr; }
      m2 = mnew;
    }
    float rs = 0.f;
    #pragma unroll
    for (int r = 0; r < 16; r++) { st0[r] = exp2f(st0[r] - m2); rs += st0[r]; }
    #pragma unroll
    for (int r = 0; r < 16; r++) { st1[r] = exp2f(st1[r] - m2); rs += st1[r]; }
    lsum += rs;
    // pack P -> bf16 B-fragments (P^T) via cvt_pk + permlane32_swap
    bfx8 pb[4];
    #pragma unroll
    for (int ks = 0; ks < 4; ks++) {
      int o = (ks & 1) * 8;
      unsigned X = cvtpk(ks < 2 ? st0[o + 0] : st1[o + 0], ks < 2 ? st0[o + 1] : st1[o + 1]);
      unsigned Z = cvtpk(ks < 2 ? st0[o + 2] : st1[o + 2], ks < 2 ? st0[o + 3] : st1[o + 3]);
      unsigned Y = cvtpk(ks < 2 ? st0[o + 4] : st1[o + 4], ks < 2 ? st0[o + 5] : st1[o + 5]);
      unsigned W = cvtpk(ks < 2 ? st0[o + 6] : st1[o + 6], ks < 2 ? st0[o + 7] : st1[o + 7]);
      swap32(X, Y);
      swap32(Z, W);
      union { unsigned u[4]; bfx8 v; } uu;
      uu.u[0] = X; uu.u[1] = Z; uu.u[2] = Y; uu.u[3] = W;
      pb[ks] = uu.v;
    }
    // O^T += V^T P^T
    #pragma unroll
    for (int ks = 0; ks < 4; ks++) {
      oacc0 = MFMA32(va[ks], pb[ks], oacc0);
      oacc1 = MFMA32(va[4 + ks], pb[ks], oacc1);
    }
    #pragma unroll
    for (int i = 0; i < 8; i++) ka[i] = kn[i];
  }
  // epilogue: normalize, per-wave LDS transpose, coalesced store
  lsum += __shfl_xor(lsum, 32);
  float inv = 1.f / lsum;
  u16* my = ot[w];
  #pragma unroll
  for (int dt = 0; dt < 2; dt++) {
    #pragma unroll
    for (int g = 0; g < 4; g++) {
      float a0 = (dt ? oacc1[g*4+0] : oacc0[g*4+0]) * inv;
      float a1 = (dt ? oacc1[g*4+1] : oacc0[g*4+1]) * inv;
      float a2 = (dt ? oacc1[g*4+2] : oacc0[g*4+2]) * inv;
      float a3 = (dt ? oacc1[g*4+3] : oacc0[g*4+3]) * inv;
      unsigned w0 = cvtpk(a0, a1), w1 = cvtpk(a2, a3);
      int d = dt * 32 + g * 8 + 4 * hi;
      int byte = (ql * 128 + d * 2) ^ ((ql & 7) << 4);
      *(uint2*)((char*)my + byte) = make_uint2(w0, w1);
    }
  }
  #pragma unroll
  for (int rr = 0; rr < 4; rr++) {
    int q = rr * 8 + (lane >> 3);
    int dk = (lane & 7) * 8;
    int byte = (q * 128 + dk * 2) ^ ((q & 7) << 4);
    uint4 val = *(uint4*)((char*)my + byte);
    *(uint4*)(Aout + ((size_t)(b * 2048) + q0 + q) * 2048 + h * 64 + dk) = val;
  }
}

// ---------- launch ----------
extern "C" void kernel_launch(void* const* d_in, const int* in_sizes, int n_in,
                              void* d_out, int out_size, void* d_ws, size_t ws_size,
                              hipStream_t stream) {
  const float* x    = (const float*)d_in[0];
  const float* cosT = (const float*)d_in[1];
  const float* sinT = (const float*)d_in[2];
  const float* Wq   = (const float*)d_in[3];
  const float* Wk   = (const float*)d_in[4];
  const float* Wv   = (const float*)d_in[5];
  const float* Wo   = (const float*)d_in[6];
  float* out = (float*)d_out;
  char* ws = (char*)d_ws;

  // workspace layout (aliased; total 88,080,384 B)
  u16* xb    = (u16*)(ws);                          // 16 MB
  u16* WqkvT = (u16*)(ws + 16777216);               // 12 MB
  u16* Qf    = (u16*)(ws);                          // alias over xb (16 MB)
  u16* Kf    = (u16*)(ws + 16777216);               // alias over WqkvT (4 MB)
  u16* Vf    = (u16*)(ws + 16777216 + 4194304);     // alias over WqkvT (4 MB)
  u16* WoT   = (u16*)(ws + 29360128);               // 8 MB
  float* Cqkv = (float*)(ws + 37748736);            // 48 MB
  u16* Aout  = (u16*)(ws + 37748736);               // alias over dead Cqkv

  dim3 tb(32, 8);
  convert_bf16_k<<<8192, 256, 0, stream>>>(x, xb, 2097152);
  transpose_k<<<dim3(64, 64), tb, 0, stream>>>(Wq, WqkvT, 2048, 2048);
  transpose_k<<<dim3(16, 64), tb, 0, stream>>>(Wk, WqkvT + (size_t)2048 * 2048, 2048, 512);
  transpose_k<<<dim3(16, 64), tb, 0, stream>>>(Wv, WqkvT + (size_t)2560 * 2048, 2048, 512);
  transpose_k<<<dim3(64, 64), tb, 0, stream>>>(Wo, WoT, 2048, 2048);

  gemm_bf16<<<dim3(24, 32), 256, 0, stream>>>(xb, WqkvT, Cqkv, 4096, 3072, 2048);

  rope_frag_k<<<2048, 256, 0, stream>>>(Cqkv, cosT, sinT, Qf, 0, 5);
  rope_frag_k<<<512, 256, 0, stream>>>(Cqkv, cosT, sinT, Kf, 2048, 3);
  vtrans_k<<<dim3(32, 16), 256, 0, stream>>>(Cqkv, Vf);

  attn_k<<<dim3(16, 32, 2), 256, 0, stream>>>(Qf, Kf, Vf, Aout);

  gemm_bf16<<<dim3(16, 32), 256, 0, stream>>>(Aout, WoT, out, 4096, 2048, 2048);
}

// Round 5
// 245.658 us; speedup vs baseline: 2.2770x; 1.1527x over previous
//
#include <hip/hip_runtime.h>

typedef unsigned short u16;
typedef __bf16 bfx8 __attribute__((ext_vector_type(8)));
typedef float f32x4 __attribute__((ext_vector_type(4)));
typedef float f32x16 __attribute__((ext_vector_type(16)));

#define MFMA16(a,b,c) __builtin_amdgcn_mfma_f32_16x16x32_bf16(a,b,c,0,0,0)
#define MFMA32(a,b,c) __builtin_amdgcn_mfma_f32_32x32x16_bf16(a,b,c,0,0,0)

// ---------- helpers ----------
__device__ __forceinline__ u16 f2bf(float f) {
  union { float f; unsigned u; } v; v.f = f;
  unsigned r = v.u + 0x7fffu + ((v.u >> 16) & 1u);   // RNE
  return (u16)(r >> 16);
}

__device__ __forceinline__ unsigned cvtpk(float lo, float hi) {
  unsigned r;
  asm("v_cvt_pk_bf16_f32 %0, %1, %2" : "=v"(r) : "v"(lo), "v"(hi));
  return r;
}

__device__ __forceinline__ void swap32(unsigned &a, unsigned &b) {
  asm("v_permlane32_swap_b32 %0, %1" : "+v"(a), "+v"(b));
}

__device__ __forceinline__ void gld16(const void* g, void* l) {
  __builtin_amdgcn_global_load_lds(
      (const __attribute__((address_space(1))) unsigned int*)g,
      (__attribute__((address_space(3))) unsigned int*)l, 16, 0, 0);
}

// ---------- f32 -> bf16 elementwise (x) ----------
__global__ void convert_bf16_k(const float* __restrict__ in, u16* __restrict__ outp, int nvec) {
  int i = blockIdx.x * 256 + threadIdx.x;
  if (i >= nvec) return;
  float4 v = ((const float4*)in)[i];
  unsigned lo = (unsigned)f2bf(v.x) | ((unsigned)f2bf(v.y) << 16);
  unsigned hi = (unsigned)f2bf(v.z) | ((unsigned)f2bf(v.w) << 16);
  ((uint2*)outp)[i] = make_uint2(lo, hi);
}

// ---------- W [K,N] f32 -> Wt [N,K] bf16 (LDS tile transpose) ----------
__global__ void transpose_k(const float* __restrict__ W, u16* __restrict__ Wt, int K, int N) {
  __shared__ float tile[32][33];
  int n0 = blockIdx.x * 32, k0 = blockIdx.y * 32;
  int tx = threadIdx.x, ty = threadIdx.y;  // (32, 8)
  #pragma unroll
  for (int i = 0; i < 4; i++)
    tile[ty * 4 + i][tx] = W[(size_t)(k0 + ty * 4 + i) * N + n0 + tx];
  __syncthreads();
  #pragma unroll
  for (int i = 0; i < 4; i++)
    Wt[(size_t)(n0 + ty * 4 + i) * K + k0 + tx] = f2bf(tile[tx][ty * 4 + i]);
}

// ---------- bf16 GEMM: C[M,N] f32 = A[M,K] @ Bt[N,K]^T  (m97 structure, XCD swizzle) ----------
__global__ __launch_bounds__(256) void gemm_bf16(
    const u16* __restrict__ A, const u16* __restrict__ Bt,
    float* __restrict__ C, int M, int N, int K)
{
  __shared__ u16 As[128 * 32];
  __shared__ u16 Bs[128 * 32];
  const int tid = threadIdx.x;
  const int lane = tid & 63, w = tid >> 6;
  const int wm = w >> 1, wn = w & 1;
  const int lrow = lane & 15, lg = lane >> 4, lk = lg * 8;
  // bijective XCD swizzle (nwg % 8 == 0 for both our grids)
  const int nwg = gridDim.x * gridDim.y;
  const int bid = blockIdx.y * gridDim.x + blockIdx.x;
  const int per = nwg >> 3;
  const int swz = (bid & 7) * per + (bid >> 3);
  const int m0 = (swz / gridDim.x) * 128, n0 = (swz % gridDim.x) * 128;
  f32x4 acc[4][4] = {};

  const int r0 = tid >> 2, kc = (tid & 3) * 8;
  const u16* Ag = A + (size_t)(m0 + r0) * K + kc;
  const u16* Bg = Bt + (size_t)(n0 + r0) * K + kc;
  u16* Al0 = As + w * 512;
  u16* Al1 = As + 2048 + w * 512;
  u16* Bl0 = Bs + w * 512;
  u16* Bl1 = Bs + 2048 + w * 512;

  for (int k0 = 0; k0 < K; k0 += 32) {
    gld16(Ag + k0, Al0);
    gld16(Ag + (size_t)64 * K + k0, Al1);
    gld16(Bg + k0, Bl0);
    gld16(Bg + (size_t)64 * K + k0, Bl1);
    __syncthreads();
    bfx8 af[4], bff[4];
    #pragma unroll
    for (int i = 0; i < 4; i++) {
      af[i]  = *(const bfx8*)(As + (wm * 64 + i * 16 + lrow) * 32 + lk);
      bff[i] = *(const bfx8*)(Bs + (wn * 64 + i * 16 + lrow) * 32 + lk);
    }
    #pragma unroll
    for (int i = 0; i < 4; i++)
      #pragma unroll
      for (int j = 0; j < 4; j++)
        acc[i][j] = MFMA16(af[i], bff[j], acc[i][j]);
    __syncthreads();
  }
  #pragma unroll
  for (int i = 0; i < 4; i++) {
    int row = m0 + wm * 64 + i * 16 + lg * 4;
    #pragma unroll
    for (int j = 0; j < 4; j++) {
      int col = n0 + wn * 64 + j * 16 + lrow;
      float* cp = C + (size_t)row * N + col;
      #pragma unroll
      for (int r = 0; r < 4; r++) cp[(size_t)r * N] = acc[i][j][r];
    }
  }
}

// ---------- RoPE -> fragment-linear Q/K ----------
// Frag layout per (b,head): regions of 2048 els per 32-row s-tile; within:
// chunk(ks, l) at (ks*64 + l)*8, holding rows s = qt*32 + (l&31),
// d = ks*16 + (l>>5)*8 .. +8.
__global__ void rope_frag_k(const float* __restrict__ Cq, const float* __restrict__ cosT,
                            const float* __restrict__ sinT, u16* __restrict__ dst,
                            int col_off, int lgnh)
{
  int t = blockIdx.x * 256 + threadIdx.x;
  int pc = t & 3;
  int h = (t >> 2) & ((1 << lgnh) - 1);
  int sm = t >> (2 + lgnh);               // b*2048 + s
  int s = sm & 2047, b = sm >> 11;
  int d0 = pc * 8;
  const float* row = Cq + (size_t)sm * 3072 + col_off + h * 64;
  float4 aA = *(const float4*)(row + d0);
  float4 aB = *(const float4*)(row + d0 + 4);
  float4 cA = *(const float4*)(row + d0 + 32);
  float4 cB = *(const float4*)(row + d0 + 36);
  const float* cr = cosT + s * 64;
  const float* sr = sinT + s * 64;
  float4 c1A = *(const float4*)(cr + d0),      c1B = *(const float4*)(cr + d0 + 4);
  float4 c2A = *(const float4*)(cr + d0 + 32), c2B = *(const float4*)(cr + d0 + 36);
  float4 s1A = *(const float4*)(sr + d0),      s1B = *(const float4*)(sr + d0 + 4);
  float4 s2A = *(const float4*)(sr + d0 + 32), s2B = *(const float4*)(sr + d0 + 36);
  float av[8] = {aA.x,aA.y,aA.z,aA.w,aB.x,aB.y,aB.z,aB.w};
  float cv[8] = {cA.x,cA.y,cA.z,cA.w,cB.x,cB.y,cB.z,cB.w};
  float c1[8] = {c1A.x,c1A.y,c1A.z,c1A.w,c1B.x,c1B.y,c1B.z,c1B.w};
  float c2[8] = {c2A.x,c2A.y,c2A.z,c2A.w,c2B.x,c2B.y,c2B.z,c2B.w};
  float s1[8] = {s1A.x,s1A.y,s1A.z,s1A.w,s1B.x,s1B.y,s1B.z,s1B.w};
  float s2[8] = {s2A.x,s2A.y,s2A.z,s2A.w,s2B.x,s2B.y,s2B.z,s2B.w};
  union { u16 h[8]; uint4 u; } o1, o2;
  #pragma unroll
  for (int j = 0; j < 8; j++) {
    o1.h[j] = f2bf(av[j] * c1[j] - cv[j] * s1[j]);
    o2.h[j] = f2bf(cv[j] * c2[j] + av[j] * s2[j]);
  }
  int qt = s >> 5, ql = s & 31;
  int ks = pc >> 1, hi = pc & 1;
  u16* base = dst + ((size_t)((b << lgnh) + h) * 64 + qt) * 2048;
  int loff = (hi * 32 + ql) * 8;
  *(uint4*)(base + ks * 512 + loff) = o1.u;
  *(uint4*)(base + (ks + 2) * 512 + loff) = o2.u;
}

// ---------- V -> fragment-linear V^T ----------
__global__ void vtrans_k(const float* __restrict__ Cq, u16* __restrict__ Vf) {
  __shared__ float tile[64][64];
  int kt = blockIdx.x;                 // 32 s-tiles of 64
  int bg = blockIdx.y; int b = bg >> 3, g = bg & 7;
  int tid = threadIdx.x;
  const float* src = Cq + (size_t)(b * 2048 + kt * 64) * 3072 + 2560 + g * 64;
  int rr = tid >> 4, c4 = (tid & 15) * 4;
  #pragma unroll
  for (int p = 0; p < 4; p++) {
    int r = p * 16 + rr;
    *(float4*)&tile[r][c4] = *(const float4*)(src + (size_t)r * 3072 + c4);
  }
  __syncthreads();
  u16* dst = Vf + (size_t)(bg * 32 + kt) * 4096;
  #pragma unroll
  for (int cc = 0; cc < 2; cc++) {
    int cid = tid * 2 + cc;
    int l = cid & 63, ks = (cid >> 6) & 3, sub = cid >> 8;
    int d = sub * 32 + (l & 31);
    int s0 = ks * 16 + (l >> 5) * 8;
    union { u16 h[8]; uint4 u; } o;
    #pragma unroll
    for (int j = 0; j < 8; j++) o.h[j] = f2bf(tile[s0 + j][d]);
    *(uint4*)(dst + cid * 8) = o.u;
  }
}

// ---------- causal flash attention, GQA — balanced pairs + fragment-linear ----------
// grid (8, H, B), 256 thr. Wave w handles q-tiles {63-qrA, qrA}, qrA=bx*4+w:
// exactly 33 K-tiles per wave -> flat occupancy. Coalesced fragment loads.
// Swapped operands: S^T = K Q^T, O^T = V^T P^T -> softmax lane-local.
__global__ __launch_bounds__(256, 2) void attn_k(
    const u16* __restrict__ Qf, const u16* __restrict__ Kf,
    const u16* __restrict__ Vf, u16* __restrict__ Aout)
{
  __shared__ u16 ot[4][32 * 64];   // per-wave epilogue transpose
  const int tid = threadIdx.x, lane = tid & 63, w = tid >> 6;
  const int h = blockIdx.y, b = blockIdx.z;
  const int kvh = h >> 2;
  const int ql = lane & 31, hi = lane >> 5;
  const int qrA = blockIdx.x * 4 + w;     // in [0,32)

  const u16* Qh = Qf + (size_t)(b * 32 + h) * 131072;
  const u16* Kp = Kf + (size_t)(b * 8 + kvh) * 131072;
  const u16* Vp = Vf + (size_t)(b * 8 + kvh) * 131072;
  const float SC = 0.125f * 1.44269504088896f;  // 1/sqrt(64) * log2(e)

  #pragma unroll
  for (int half = 0; half < 2; half++) {
    const int qr = half ? qrA : 63 - qrA;
    const int q0 = qr * 32;
    const int qg = q0 + ql;
    const int nkt = qr / 2 + 1;

    bfx8 qf[4];
    #pragma unroll
    for (int ks = 0; ks < 4; ks++)
      qf[ks] = *(const bfx8*)(Qh + (size_t)qr * 2048 + ks * 512 + lane * 8);

    f32x16 oacc0 = {}, oacc1 = {};
    float m2 = -3.0e38f;
    float lsum = 0.f;

    // prefetch K-tile 0 (coalesced: 64 lanes x 16B consecutive)
    bfx8 ka[8];
    #pragma unroll
    for (int i = 0; i < 8; i++)
      ka[i] = *(const bfx8*)(Kp + i * 512 + lane * 8);

    for (int kt = 0; kt < nkt; kt++) {
      const int kb = kt * 64;
      // V loads for this tile (consumed after softmax)
      bfx8 va[8];
      #pragma unroll
      for (int i = 0; i < 8; i++)
        va[i] = *(const bfx8*)(Vp + (size_t)kt * 4096 + i * 512 + lane * 8);
      // S^T = K Q^T from prefetched ka
      f32x16 st0 = {}, st1 = {};
      #pragma unroll
      for (int ks = 0; ks < 4; ks++) {
        st0 = MFMA32(ka[ks], qf[ks], st0);
        st1 = MFMA32(ka[4 + ks], qf[ks], st1);
      }
      // K loads for next tile
      const int ktn = (kt + 1 < nkt) ? kt + 1 : 0;
      bfx8 kn[8];
      #pragma unroll
      for (int i = 0; i < 8; i++)
        kn[i] = *(const bfx8*)(Kp + (size_t)ktn * 4096 + i * 512 + lane * 8);
      // scale (+ causal mask on last tile), in place
      #pragma unroll
      for (int r = 0; r < 16; r++) { st0[r] *= SC; st1[r] *= SC; }
      if (kt == nkt - 1) {
        #pragma unroll
        for (int r = 0; r < 16; r++) {
          int crow = (r & 3) + 8 * (r >> 2) + 4 * hi;
          if (kb + crow > qg) st0[r] = -3.0e38f;
          if (kb + 32 + crow > qg) st1[r] = -3.0e38f;
        }
      }
      // tree max (depth 6 instead of 31-deep chain)
      float mx[16];
      #pragma unroll
      for (int r = 0; r < 16; r++) mx[r] = fmaxf(st0[r], st1[r]);
      #pragma unroll
      for (int s = 8; s > 0; s >>= 1)
        #pragma unroll
        for (int r = 0; r < s; r++) mx[r] = fmaxf(mx[r], mx[r + s]);
      float tm = fmaxf(mx[0], __shfl_xor(mx[0], 32));
      float mnew = fmaxf(m2, tm);
      if (!__all(tm <= m2 + 8.0f)) {
        float corr = exp2f(m2 - mnew);
        lsum *= corr;
        #pragma unroll
        for (int i = 0; i < 16; i++) { oacc0[i] *= corr; oacc1[i] *= corr; }
        m2 = mnew;
      }
      #pragma unroll
      for (int r = 0; r < 16; r++) { st0[r] = exp2f(st0[r] - m2); }
      #pragma unroll
      for (int r = 0; r < 16; r++) { st1[r] = exp2f(st1[r] - m2); }
      // tree sum
      float sm[16];
      #pragma unroll
      for (int r = 0; r < 16; r++) sm[r] = st0[r] + st1[r];
      #pragma unroll
      for (int s = 8; s > 0; s >>= 1)
        #pragma unroll
        for (int r = 0; r < s; r++) sm[r] += sm[r + s];
      lsum += sm[0];
      // pack P -> bf16 B-fragments (P^T) via cvt_pk + permlane32_swap
      bfx8 pb[4];
      #pragma unroll
      for (int ks = 0; ks < 4; ks++) {
        int o = (ks & 1) * 8;
        unsigned X = cvtpk(ks < 2 ? st0[o + 0] : st1[o + 0], ks < 2 ? st0[o + 1] : st1[o + 1]);
        unsigned Z = cvtpk(ks < 2 ? st0[o + 2] : st1[o + 2], ks < 2 ? st0[o + 3] : st1[o + 3]);
        unsigned Y = cvtpk(ks < 2 ? st0[o + 4] : st1[o + 4], ks < 2 ? st0[o + 5] : st1[o + 5]);
        unsigned W = cvtpk(ks < 2 ? st0[o + 6] : st1[o + 6], ks < 2 ? st0[o + 7] : st1[o + 7]);
        swap32(X, Y);
        swap32(Z, W);
        union { unsigned u[4]; bfx8 v; } uu;
        uu.u[0] = X; uu.u[1] = Z; uu.u[2] = Y; uu.u[3] = W;
        pb[ks] = uu.v;
      }
      // O^T += V^T P^T
      #pragma unroll
      for (int ks = 0; ks < 4; ks++) {
        oacc0 = MFMA32(va[ks], pb[ks], oacc0);
        oacc1 = MFMA32(va[4 + ks], pb[ks], oacc1);
      }
      #pragma unroll
      for (int i = 0; i < 8; i++) ka[i] = kn[i];
    }
    // epilogue: normalize, per-wave LDS transpose, coalesced store
    lsum += __shfl_xor(lsum, 32);
    float inv = 1.f / lsum;
    u16* my = ot[w];
    #pragma unroll
    for (int dt = 0; dt < 2; dt++) {
      #pragma unroll
      for (int g = 0; g < 4; g++) {
        float a0 = (dt ? oacc1[g*4+0] : oacc0[g*4+0]) * inv;
        float a1 = (dt ? oacc1[g*4+1] : oacc0[g*4+1]) * inv;
        float a2 = (dt ? oacc1[g*4+2] : oacc0[g*4+2]) * inv;
        float a3 = (dt ? oacc1[g*4+3] : oacc0[g*4+3]) * inv;
        unsigned w0 = cvtpk(a0, a1), w1 = cvtpk(a2, a3);
        int d = dt * 32 + g * 8 + 4 * hi;
        int byte = (ql * 128 + d * 2) ^ ((ql & 7) << 4);
        *(uint2*)((char*)my + byte) = make_uint2(w0, w1);
      }
    }
    #pragma unroll
    for (int rr = 0; rr < 4; rr++) {
      int q = rr * 8 + (lane >> 3);
      int dk = (lane & 7) * 8;
      int byte = (q * 128 + dk * 2) ^ ((q & 7) << 4);
      uint4 val = *(uint4*)((char*)my + byte);
      *(uint4*)(Aout + ((size_t)(b * 2048) + q0 + q) * 2048 + h * 64 + dk) = val;
    }
  }
}

// ---------- launch ----------
extern "C" void kernel_launch(void* const* d_in, const int* in_sizes, int n_in,
                              void* d_out, int out_size, void* d_ws, size_t ws_size,
                              hipStream_t stream) {
  const float* x    = (const float*)d_in[0];
  const float* cosT = (const float*)d_in[1];
  const float* sinT = (const float*)d_in[2];
  const float* Wq   = (const float*)d_in[3];
  const float* Wk   = (const float*)d_in[4];
  const float* Wv   = (const float*)d_in[5];
  const float* Wo   = (const float*)d_in[6];
  float* out = (float*)d_out;
  char* ws = (char*)d_ws;

  // workspace layout (aliased; total 88,080,384 B)
  u16* xb    = (u16*)(ws);                          // 16 MB
  u16* WqkvT = (u16*)(ws + 16777216);               // 12 MB
  u16* Qf    = (u16*)(ws);                          // alias over xb (16 MB)
  u16* Kf    = (u16*)(ws + 16777216);               // alias over WqkvT (4 MB)
  u16* Vf    = (u16*)(ws + 16777216 + 4194304);     // alias over WqkvT (4 MB)
  u16* WoT   = (u16*)(ws + 29360128);               // 8 MB
  float* Cqkv = (float*)(ws + 37748736);            // 48 MB
  u16* Aout  = (u16*)(ws + 37748736);               // alias over dead Cqkv

  dim3 tb(32, 8);
  convert_bf16_k<<<8192, 256, 0, stream>>>(x, xb, 2097152);
  transpose_k<<<dim3(64, 64), tb, 0, stream>>>(Wq, WqkvT, 2048, 2048);
  transpose_k<<<dim3(16, 64), tb, 0, stream>>>(Wk, WqkvT + (size_t)2048 * 2048, 2048, 512);
  transpose_k<<<dim3(16, 64), tb, 0, stream>>>(Wv, WqkvT + (size_t)2560 * 2048, 2048, 512);
  transpose_k<<<dim3(64, 64), tb, 0, stream>>>(Wo, WoT, 2048, 2048);

  gemm_bf16<<<dim3(24, 32), 256, 0, stream>>>(xb, WqkvT, Cqkv, 4096, 3072, 2048);

  rope_frag_k<<<2048, 256, 0, stream>>>(Cqkv, cosT, sinT, Qf, 0, 5);
  rope_frag_k<<<512, 256, 0, stream>>>(Cqkv, cosT, sinT, Kf, 2048, 3);
  vtrans_k<<<dim3(32, 16), 256, 0, stream>>>(Cqkv, Vf);

  attn_k<<<dim3(8, 32, 2), 256, 0, stream>>>(Qf, Kf, Vf, Aout);

  gemm_bf16<<<dim3(16, 32), 256, 0, stream>>>(Aout, WoT, out, 4096, 2048, 2048);
}